// Round 19
// baseline (208.861 us; speedup 1.0000x reference)
//
#include <hip/hip_runtime.h>
#include <hip/hip_bf16.h>
#include <math.h>

#define NCHUNK 256
#define CLEN 16   // NCHUNK * CLEN == 4096

typedef __attribute__((ext_vector_type(8))) short short8;
typedef __attribute__((ext_vector_type(4))) float f32x4;

__device__ __forceinline__ void gload16(const void* g, void* l) {
  __builtin_amdgcn_global_load_lds(
      (const __attribute__((address_space(1))) void*)g,
      (__attribute__((address_space(3))) void*)l, 16, 0, 0);
}

__device__ __forceinline__ float bf2f(short s) {
  unsigned int u = ((unsigned int)(unsigned short)s) << 16;
  return __uint_as_float(u);
}
__device__ __forceinline__ short f2bf(float f) {
  __hip_bfloat16 h = __float2bfloat16(f);
  return *reinterpret_cast<short*>(&h);
}

// E^(n+1) for n=0..15 via log-depth product tree (14 muls, depth ~4)
__device__ __forceinline__ void pow_tree(float E, float g[16]) {
  g[0] = E;          g[1] = E * E;        g[2] = g[1] * E;     g[3] = g[1] * g[1];
  g[4] = g[3] * E;   g[5] = g[3] * g[1];  g[6] = g[5] * E;     g[7] = g[3] * g[3];
  g[8] = g[7] * E;   g[9] = g[7] * g[1];  g[10] = g[9] * E;    g[11] = g[7] * g[3];
  g[12] = g[11] * E; g[13] = g[11] * g[1]; g[14] = g[13] * E;  g[15] = g[7] * g[7];
}

// ---------------- A_log structure check: flag=1 iff a[d][n] == -(n+1) --------
// 1 block, 256 threads; each checks 64 of the 2*512*16 entries.
__global__ __launch_bounds__(256) void check_alog(
    const float* __restrict__ Alog_fw, const float* __restrict__ Alog_bw,
    int* __restrict__ flag)
{
  __shared__ int ok;
  int tid = threadIdx.x;
  if (tid == 0) ok = 1;
  __syncthreads();
  int good = 1;
  for (int e = tid * 64; e < tid * 64 + 64; e++) {
    int dir = e >> 13, rest = e & 8191;
    int n = rest & 15;
    const float* Alog = dir ? Alog_bw : Alog_fw;
    float av = __expf(Alog[rest]);
    good = good && (fabsf(av - (float)(n + 1)) < 1e-4f * (float)(n + 1));
  }
  if (!good) atomicAnd(&ok, 0);
  __syncthreads();
  if (tid == 0) *flag = ok;
}

// ---------------- weight cast: 6 fp32 tensors -> one contiguous bf16 buffer --
__global__ __launch_bounds__(256) void cast_weights(
    const float* __restrict__ a0, const float* __restrict__ a1,
    const float* __restrict__ a2, const float* __restrict__ a3,
    const float* __restrict__ a4, const float* __restrict__ a5,
    __hip_bfloat16* __restrict__ dst)
{
  int gid = blockIdx.x * 256 + threadIdx.x;
  if (gid >= 835584) return;
  int off = gid; const float* s;
  if (off < 262144) s = a0;
  else if ((off -= 262144) < 262144) s = a1;
  else if ((off -= 262144) < 131072) s = a2;
  else if ((off -= 131072) < 131072) s = a3;
  else if ((off -= 131072) < 24576) s = a4;
  else { off -= 24576; s = a5; }
  dst[gid] = __float2bfloat16(s[off]);
}

// ---------------- RMSNorm: both dirs in one pass ----------------
__global__ __launch_bounds__(256) void rmsnorm_kernel(
    const float* __restrict__ x,
    const float* __restrict__ w_fw, const float* __restrict__ w_bw,
    __hip_bfloat16* __restrict__ xnh)
{
  int row = blockIdx.x;          // b*4096 + l
  int tid = threadIdx.x;
  float v = x[row * 256 + tid];
  float ss = v * v;
  #pragma unroll
  for (int m = 32; m; m >>= 1) ss += __shfl_xor(ss, m, 64);
  __shared__ float red[4];
  if ((tid & 63) == 0) red[tid >> 6] = ss;
  __syncthreads();
  float tot = red[0] + red[1] + red[2] + red[3];
  float sc = rsqrtf(tot / 256.f + 1e-5f);
  float vs = v * sc;
  xnh[(size_t)row * 256 + tid] = __float2bfloat16(vs * w_fw[tid]);
  xnh[((size_t)8192 + row) * 256 + tid] = __float2bfloat16(vs * w_bw[tid]);
}

// ---------------- bf16 MFMA GEMM, both dirs batched via blockIdx.z ----------
__global__ __launch_bounds__(256) void gemm_mfma(
    const __hip_bfloat16* __restrict__ A, size_t aStr, int lda,
    const __hip_bfloat16* __restrict__ B0, const __hip_bfloat16* __restrict__ B1,
    int ldb,
    void* __restrict__ C, size_t cStr, int ldc,
    int M, int N, int K,
    int epi, const float* __restrict__ ep_mat, int ep_ld, int obf)
{
  __shared__ __align__(16) __hip_bfloat16 As[128 * 32];
  __shared__ __align__(16) __hip_bfloat16 Bs[128 * 32];
  int tid = threadIdx.x;
  int lane = tid & 63, wid = tid >> 6;
  int dir = blockIdx.z;
  const __hip_bfloat16* Ad = A + (size_t)dir * aStr;
  const __hip_bfloat16* Bd = dir ? B1 : B0;
  int m0 = blockIdx.x * 128, n0 = blockIdx.y * 128;
  int wr = wid & 1, wc = wid >> 1;

  f32x4 acc[4][4] = {};

  int lrow = lane >> 2;
  int lk8  = (lane & 3) * 8;

  for (int k0 = 0; k0 < K; k0 += 32) {
    __syncthreads();
    #pragma unroll
    for (int s = 0; s < 2; s++) {
      int r = wid * 2 + s;
      int arow = m0 + r * 16 + lrow;
      gload16(Ad + (size_t)arow * lda + k0 + lk8, &As[r * 512]);
      int brow = n0 + r * 16 + lrow;
      if (brow > N - 1) brow = N - 1;
      gload16(Bd + (size_t)brow * ldb + k0 + lk8, &Bs[r * 512]);
    }
    __syncthreads();

    short8 af[4], bfr[4];
    #pragma unroll
    for (int i = 0; i < 4; i++)
      af[i] = *(const short8*)&As[(wr * 64 + i * 16 + (lane & 15)) * 32 + (lane >> 4) * 8];
    #pragma unroll
    for (int j = 0; j < 4; j++)
      bfr[j] = *(const short8*)&Bs[(wc * 64 + j * 16 + (lane & 15)) * 32 + (lane >> 4) * 8];
    #pragma unroll
    for (int i = 0; i < 4; i++)
      #pragma unroll
      for (int j = 0; j < 4; j++)
        acc[i][j] = __builtin_amdgcn_mfma_f32_16x16x32_bf16(af[i], bfr[j], acc[i][j], 0, 0, 0);
  }

  int crow = (lane >> 4) * 4;
  int ccol = lane & 15;
  #pragma unroll
  for (int i = 0; i < 4; i++) {
    #pragma unroll
    for (int j = 0; j < 4; j++) {
      int nn = n0 + wc * 64 + j * 16 + ccol;
      if (nn < N) {
        #pragma unroll
        for (int q = 0; q < 4; q++) {
          int mm = m0 + wr * 64 + i * 16 + crow + q;
          float v = acc[i][j][q];
          if (obf) {
            ((__hip_bfloat16*)C)[(size_t)dir * cStr + (size_t)mm * ldc + nn] =
                __float2bfloat16(v);
          } else {
            if (epi == 2) v += ep_mat[(size_t)mm * ep_ld + nn];
            ((float*)C)[(size_t)dir * cStr + (size_t)mm * ldc + nn] = v;
          }
        }
      }
    }
  }
}

// ---------------- fp32 GEMM (dt path, K=16), dirs batched --------------------
__global__ __launch_bounds__(256) void gemm_bt(
    const float* __restrict__ A, size_t aStr, int lda,
    const float* __restrict__ B0, const float* __restrict__ B1, int ldb,
    void* __restrict__ C, size_t cStr, int ldc,
    int M, int N, int K,
    int epi, const float* __restrict__ ev0, const float* __restrict__ ev1,
    int obf)
{
  __shared__ float As[16][64];
  __shared__ float Bs[16][64];
  int tid = threadIdx.x;
  int dir = blockIdx.z;
  const float* Ad = A + (size_t)dir * aStr;
  const float* Bd = dir ? B1 : B0;
  const float* ep_vec = dir ? ev1 : ev0;
  int tx = tid & 15, ty = tid >> 4;
  int m0 = blockIdx.x * 64, n0 = blockIdx.y * 64;
  int lr = tid >> 2;
  int lk = (tid & 3) << 2;
  float acc[4][4] = {};

  for (int k0 = 0; k0 < K; k0 += 16) {
    float4 av = *(const float4*)&Ad[(size_t)(m0 + lr) * lda + k0 + lk];
    float4 bv = make_float4(0.f, 0.f, 0.f, 0.f);
    if (n0 + lr < N) bv = *(const float4*)&Bd[(size_t)(n0 + lr) * ldb + k0 + lk];
    __syncthreads();
    As[lk + 0][lr] = av.x; As[lk + 1][lr] = av.y;
    As[lk + 2][lr] = av.z; As[lk + 3][lr] = av.w;
    Bs[lk + 0][lr] = bv.x; Bs[lk + 1][lr] = bv.y;
    Bs[lk + 2][lr] = bv.z; Bs[lk + 3][lr] = bv.w;
    __syncthreads();
    #pragma unroll
    for (int kk = 0; kk < 16; kk++) {
      float4 a4 = *(const float4*)&As[kk][ty << 2];
      float4 b4 = *(const float4*)&Bs[kk][tx << 2];
      float ar[4] = {a4.x, a4.y, a4.z, a4.w};
      float br[4] = {b4.x, b4.y, b4.z, b4.w};
      #pragma unroll
      for (int i = 0; i < 4; i++)
        #pragma unroll
        for (int j = 0; j < 4; j++)
          acc[i][j] = fmaf(ar[i], br[j], acc[i][j]);
    }
  }

  #pragma unroll
  for (int i = 0; i < 4; i++) {
    int m = m0 + (ty << 2) + i;
    #pragma unroll
    for (int j = 0; j < 4; j++) {
      int n = n0 + (tx << 2) + j;
      if (n < N) {
        float v = acc[i][j];
        if (epi == 1) {
          v += ep_vec[n];
          v = fmaxf(v, 0.f) + log1pf(__expf(-fabsf(v)));  // stable softplus
        }
        if (obf) ((__hip_bfloat16*)C)[(size_t)dir * cStr + (size_t)m * ldc + n] =
                     __float2bfloat16(v);
        else     ((float*)C)[(size_t)dir * cStr + (size_t)m * ldc + n] = v;
      }
    }
  }
}

// ---------------- Depthwise causal conv(4) + SiLU, 8 ch x 8 rows / thread ----
__global__ __launch_bounds__(256) void conv_silu_kernel(
    const __hip_bfloat16* __restrict__ xzh,
    const float* __restrict__ cw_fw, const float* __restrict__ cb_fw,
    const float* __restrict__ cw_bw, const float* __restrict__ cb_bw,
    __hip_bfloat16* __restrict__ xch)
{
  int dir = blockIdx.y;
  int gid = blockIdx.x * 256 + threadIdx.x;   // 64 dg-groups x 1024 row-groups
  int dg = (gid & 63) * 8;
  int rg = gid >> 6;           // 0..1023
  int b  = rg >> 9;            // batch
  int p0 = (rg & 511) * 8;     // 8-row group within sequence
  const float* cw = dir ? cw_bw : cw_fw;
  const float* cb = dir ? cb_bw : cb_fw;
  const __hip_bfloat16* xi = xzh + (size_t)dir * 8192 * 1024;

  float4 w4[8]; float bias[8];
  #pragma unroll
  for (int k = 0; k < 8; k++) {
    w4[k] = *(const float4*)&cw[(dg + k) * 4];
    bias[k] = cb[dg + k];
  }

  size_t rowbase = (size_t)(b * 4096) * 1024 + dg;
  int step = dir ? -1 : 1;
  int pstart = dir ? p0 + 7 : p0;

  short8 zero = {0, 0, 0, 0, 0, 0, 0, 0};
  short8 win0 = zero, win1 = zero, win2 = zero;
  {
    int pp = pstart - 3 * step;
    if (pp >= 0 && pp < 4096) win0 = *(const short8*)&xi[rowbase + (size_t)pp * 1024];
    pp = pstart - 2 * step;
    if (pp >= 0 && pp < 4096) win1 = *(const short8*)&xi[rowbase + (size_t)pp * 1024];
    pp = pstart - step;
    if (pp >= 0 && pp < 4096) win2 = *(const short8*)&xi[rowbase + (size_t)pp * 1024];
  }

  #pragma unroll
  for (int i = 0; i < 8; i++) {
    int prow = pstart + step * i;
    short8 cur = *(const short8*)&xi[rowbase + (size_t)prow * 1024];
    short8 o;
    #pragma unroll
    for (int k = 0; k < 8; k++) {
      float acc = bias[k];
      acc = fmaf(w4[k].x, bf2f(win0[k]), acc);
      acc = fmaf(w4[k].y, bf2f(win1[k]), acc);
      acc = fmaf(w4[k].z, bf2f(win2[k]), acc);
      acc = fmaf(w4[k].w, bf2f(cur[k]),  acc);
      float s = acc / (1.f + __expf(-acc));
      o[k] = f2bf(s);
    }
    *(short8*)&xch[((size_t)dir * 8192 + b * 4096 + prow) * 512 + dg] = o;
    win0 = win1; win1 = win2; win2 = cur;
  }
}

// ---------------- Chunked selective scan (dt precomputed, bf16 inputs) ------
// Fast path (flag-verified A_log structure): a[n] = -(n+1) exactly, gates via
// pow_tree of E = exp(-dt); no Alog loads, no setup exps. Generic fallback.
// Phase 1: per-chunk (Ac, Bc) bf16. grid (2, NCHUNK, 4), block 256
__global__ __launch_bounds__(256) void scan_part1(
    const __hip_bfloat16* __restrict__ xch, const __hip_bfloat16* __restrict__ dtbh,
    const float* __restrict__ dbl,
    const float* __restrict__ Alog_fw, const float* __restrict__ Alog_bw,
    const int* __restrict__ aflag,
    __hip_bfloat16* __restrict__ Ac, __hip_bfloat16* __restrict__ Bc)
{
  int tid = threadIdx.x;
  int d = blockIdx.x * 256 + tid;
  int c = blockIdx.y, bd = blockIdx.z, dir = bd >> 1;
  bool fast = (*aflag != 0);

  float h[16];
  #pragma unroll
  for (int n = 0; n < 16; n++) h[n] = 0.f;

  int base = bd * 4096;
  int stepw = dir ? -1 : 1;
  int t0 = c * CLEN;
  int r = base + (dir ? 4095 - t0 : t0);

  float dtv = __bfloat162float(dtbh[(size_t)r * 512 + d]);
  float uv  = __bfloat162float(xch[(size_t)r * 512 + d]);
  float sdt = 0.f;

  if (fast) {
    for (int i = 0; i < CLEN; i++) {
      const float* row = dbl + (size_t)r * 48 + 16;
      float dt_c = dtv, u_c = uv;
      if (i < CLEN - 1) {
        dtv = __bfloat162float(dtbh[(size_t)(r + stepw) * 512 + d]);
        uv  = __bfloat162float(xch[(size_t)(r + stepw) * 512 + d]);
      }
      sdt += dt_c;
      float dtu = dt_c * u_c;
      float g[16];
      pow_tree(__expf(-dt_c), g);
      #pragma unroll
      for (int n = 0; n < 16; n++)
        h[n] = fmaf(g[n], h[n], dtu * row[n]);
      r += stepw;
    }
  } else {
    const float* Alog = dir ? Alog_bw : Alog_fw;
    float a[16];
    #pragma unroll
    for (int n = 0; n < 16; n++) a[n] = -__expf(Alog[d * 16 + n]);
    for (int i = 0; i < CLEN; i++) {
      const float* row = dbl + (size_t)r * 48 + 16;
      float dt_c = dtv, u_c = uv;
      if (i < CLEN - 1) {
        dtv = __bfloat162float(dtbh[(size_t)(r + stepw) * 512 + d]);
        uv  = __bfloat162float(xch[(size_t)(r + stepw) * 512 + d]);
      }
      sdt += dt_c;
      float dtu = dt_c * u_c;
      #pragma unroll
      for (int n = 0; n < 16; n++) {
        float g = __expf(dt_c * a[n]);
        h[n] = fmaf(g, h[n], dtu * row[n]);
      }
      r += stepw;
    }
  }

  size_t ob = (((size_t)bd * NCHUNK + c) * 512 + d) * 16;
  float A16[16];
  if (fast) {
    pow_tree(__expf(-sdt), A16);
  } else {
    const float* Alog = dir ? Alog_bw : Alog_fw;
    #pragma unroll
    for (int n = 0; n < 16; n++)
      A16[n] = __expf(-__expf(Alog[d * 16 + n]) * sdt);
  }
  short8 av0, av1, bv0, bv1;
  #pragma unroll
  for (int n = 0; n < 8; n++) {
    av0[n] = f2bf(A16[n]);
    av1[n] = f2bf(A16[8 + n]);
    bv0[n] = f2bf(h[n]);
    bv1[n] = f2bf(h[8 + n]);
  }
  *(short8*)&Ac[ob]     = av0;
  *(short8*)&Ac[ob + 8] = av1;
  *(short8*)&Bc[ob]     = bv0;
  *(short8*)&Bc[ob + 8] = bv1;
}

// Phase 2: sequential composition over chunks; bf16 in/out, fp32 accum.
__global__ __launch_bounds__(256) void scan_mid(
    const __hip_bfloat16* __restrict__ Ac, const __hip_bfloat16* __restrict__ Bc,
    __hip_bfloat16* __restrict__ HinB)
{
  int gid = blockIdx.x * 256 + threadIdx.x;   // 0..32767
  int bd = gid >> 13, pos = gid & 8191;
  size_t idx = (size_t)bd * NCHUNK * 8192 + pos;
  float h = 0.f;
  float av = __bfloat162float(Ac[idx]), bv = __bfloat162float(Bc[idx]);
  for (int c = 0; c < NCHUNK; c++) {
    float a0 = av, b0 = bv;
    if (c < NCHUNK - 1) {
      av = __bfloat162float(Ac[idx + 8192]);
      bv = __bfloat162float(Bc[idx + 8192]);
    }
    HinB[idx] = __float2bfloat16(h);
    h = fmaf(a0, h, b0);
    idx += 8192;
  }
}

// Phase 3: local rescan from Hin, emit y (bf16). grid (2, NCHUNK, 4)
__global__ __launch_bounds__(256) void scan_part2(
    const __hip_bfloat16* __restrict__ xzh, const __hip_bfloat16* __restrict__ xch,
    const __hip_bfloat16* __restrict__ dtbh, const float* __restrict__ dbl,
    const float* __restrict__ Alog_fw, const float* __restrict__ Alog_bw,
    const float* __restrict__ Dp_fw, const float* __restrict__ Dp_bw,
    const int* __restrict__ aflag,
    const __hip_bfloat16* __restrict__ HinB, __hip_bfloat16* __restrict__ yvh)
{
  int tid = threadIdx.x;
  int d = blockIdx.x * 256 + tid;
  int c = blockIdx.y, bd = blockIdx.z, dir = bd >> 1;
  float Dd = (dir ? Dp_bw : Dp_fw)[d];
  bool fast = (*aflag != 0);

  float h[16];
  size_t ob = (((size_t)bd * NCHUNK + c) * 512 + d) * 16;
  #pragma unroll
  for (int n = 0; n < 16; n++) h[n] = __bfloat162float(HinB[ob + n]);

  int base = bd * 4096;
  int stepw = dir ? -1 : 1;
  int t0 = c * CLEN;
  int r = base + (dir ? 4095 - t0 : t0);

  float dtv = __bfloat162float(dtbh[(size_t)r * 512 + d]);
  float uv  = __bfloat162float(xch[(size_t)r * 512 + d]);
  float zv  = __bfloat162float(xzh[(size_t)r * 1024 + 512 + d]);

  if (fast) {
    for (int i = 0; i < CLEN; i++) {
      const float* row = dbl + (size_t)r * 48 + 16;
      float dt_c = dtv, u_c = uv, z_c = zv;
      int rc = r;
      if (i < CLEN - 1) {
        dtv = __bfloat162float(dtbh[(size_t)(r + stepw) * 512 + d]);
        uv  = __bfloat162float(xch[(size_t)(r + stepw) * 512 + d]);
        zv  = __bfloat162float(xzh[(size_t)(r + stepw) * 1024 + 512 + d]);
      }
      float dtu = dt_c * u_c;
      float g[16];
      pow_tree(__expf(-dt_c), g);
      float y0 = 0.f, y1 = 0.f, y2 = 0.f, y3 = 0.f;
      #pragma unroll
      for (int n = 0; n < 4; n++) {
        h[n]      = fmaf(g[n],      h[n],      dtu * row[n]);
        h[n + 4]  = fmaf(g[n + 4],  h[n + 4],  dtu * row[n + 4]);
        h[n + 8]  = fmaf(g[n + 8],  h[n + 8],  dtu * row[n + 8]);
        h[n + 12] = fmaf(g[n + 12], h[n + 12], dtu * row[n + 12]);
        y0 = fmaf(h[n],      row[16 + n],      y0);
        y1 = fmaf(h[n + 4],  row[16 + n + 4],  y1);
        y2 = fmaf(h[n + 8],  row[16 + n + 8],  y2);
        y3 = fmaf(h[n + 12], row[16 + n + 12], y3);
      }
      float y = (y0 + y1) + (y2 + y3);
      float sz = z_c / (1.f + __expf(-z_c));
      yvh[(size_t)rc * 512 + d] = __float2bfloat16((y + Dd * u_c) * sz);
      r += stepw;
    }
  } else {
    const float* Alog = dir ? Alog_bw : Alog_fw;
    float a[16];
    #pragma unroll
    for (int n = 0; n < 16; n++) a[n] = -__expf(Alog[d * 16 + n]);
    for (int i = 0; i < CLEN; i++) {
      const float* row = dbl + (size_t)r * 48 + 16;
      float dt_c = dtv, u_c = uv, z_c = zv;
      int rc = r;
      if (i < CLEN - 1) {
        dtv = __bfloat162float(dtbh[(size_t)(r + stepw) * 512 + d]);
        uv  = __bfloat162float(xch[(size_t)(r + stepw) * 512 + d]);
        zv  = __bfloat162float(xzh[(size_t)(r + stepw) * 1024 + 512 + d]);
      }
      float dtu = dt_c * u_c;
      float y0 = 0.f, y1 = 0.f, y2 = 0.f, y3 = 0.f;
      #pragma unroll
      for (int n = 0; n < 4; n++) {
        h[n]      = fmaf(__expf(dt_c * a[n]),      h[n],      dtu * row[n]);
        h[n + 4]  = fmaf(__expf(dt_c * a[n + 4]),  h[n + 4],  dtu * row[n + 4]);
        h[n + 8]  = fmaf(__expf(dt_c * a[n + 8]),  h[n + 8],  dtu * row[n + 8]);
        h[n + 12] = fmaf(__expf(dt_c * a[n + 12]), h[n + 12], dtu * row[n + 12]);
        y0 = fmaf(h[n],      row[16 + n],      y0);
        y1 = fmaf(h[n + 4],  row[16 + n + 4],  y1);
        y2 = fmaf(h[n + 8],  row[16 + n + 8],  y2);
        y3 = fmaf(h[n + 12], row[16 + n + 12], y3);
      }
      float y = (y0 + y1) + (y2 + y3);
      float sz = z_c / (1.f + __expf(-z_c));
      yvh[(size_t)rc * 512 + d] = __float2bfloat16((y + Dd * u_c) * sz);
      r += stepw;
    }
  }
}

extern "C" void kernel_launch(void* const* d_in, const int* in_sizes, int n_in,
                              void* d_out, int out_size, void* d_ws, size_t ws_size,
                              hipStream_t stream)
{
  const float* x = (const float*)d_in[0];
  const float* nw[2]     = {(const float*)d_in[1],  (const float*)d_in[11]};
  const float* inp[2]    = {(const float*)d_in[2],  (const float*)d_in[12]};
  const float* cw[2]     = {(const float*)d_in[3],  (const float*)d_in[13]};
  const float* cb[2]     = {(const float*)d_in[4],  (const float*)d_in[14]};
  const float* xp[2]     = {(const float*)d_in[5],  (const float*)d_in[15]};
  const float* dtw[2]    = {(const float*)d_in[6],  (const float*)d_in[16]};
  const float* dtbias[2] = {(const float*)d_in[7],  (const float*)d_in[17]};
  const float* alog[2]   = {(const float*)d_in[8],  (const float*)d_in[18]};
  const float* dvec[2]   = {(const float*)d_in[9],  (const float*)d_in[19]};
  const float* outp[2]   = {(const float*)d_in[10], (const float*)d_in[20]};

  float* ws = (float*)d_ws;
  size_t F = 0;
  __hip_bfloat16* xzh = (__hip_bfloat16*)(ws + F);      // bf16 2*8192*1024
  F += (size_t)2 * 8192 * 512;
  __hip_bfloat16* xch = (__hip_bfloat16*)(ws + F);      // bf16 2*8192*512
  F += (size_t)2 * 8192 * 256;
  float* dbl = ws + F;  F += (size_t)2 * 8192 * 48;
  __hip_bfloat16* dtbh = (__hip_bfloat16*)(ws + F);     // bf16 2*8192*512
  F += (size_t)2 * 8192 * 256;
  __hip_bfloat16* Ac = (__hip_bfloat16*)(ws + F);       // bf16 4*NCHUNK*8192
  F += (size_t)2 * NCHUNK * 8192;
  __hip_bfloat16* Bc = (__hip_bfloat16*)(ws + F);       // bf16 4*NCHUNK*8192
  F += (size_t)2 * NCHUNK * 8192;
  __hip_bfloat16* yvh = (__hip_bfloat16*)(ws + F);      // bf16 2*8192*512
  F += (size_t)2 * 8192 * 256;
  __hip_bfloat16* xnh = (__hip_bfloat16*)(ws + F);      // bf16 2*8192*256
  F += (size_t)2 * 8192 * 128;
  __hip_bfloat16* wb  = (__hip_bfloat16*)(ws + F);      // bf16 835584
  F += 835584 / 2;
  int* aflag = (int*)(ws + F);  F += 1;
  __hip_bfloat16* HinB = (__hip_bfloat16*)d_out;  // 8.39M bf16 = d_out exactly
  float* out = (float*)d_out;

  __hip_bfloat16* w_in[2]  = {wb,            wb + 262144};
  __hip_bfloat16* w_out[2] = {wb + 524288,   wb + 655360};
  __hip_bfloat16* w_xp[2]  = {wb + 786432,   wb + 811008};

  check_alog<<<dim3(1), 256, 0, stream>>>(alog[0], alog[1], aflag);

  cast_weights<<<dim3(3264), 256, 0, stream>>>(
      inp[0], inp[1], outp[0], outp[1], xp[0], xp[1], wb);

  rmsnorm_kernel<<<dim3(8192), 256, 0, stream>>>(x, nw[0], nw[1], xnh);

  // in_proj: (8192x256)bf16 @ (1024x256)^T bf16 -> bf16 (8192x1024), both dirs
  gemm_mfma<<<dim3(64, 8, 2), 256, 0, stream>>>(
      xnh, (size_t)8192 * 256, 256,
      w_in[0], w_in[1], 256,
      xzh, (size_t)8192 * 1024, 1024,
      8192, 1024, 256, 0, nullptr, 0, 1);

  conv_silu_kernel<<<dim3(256, 2), 256, 0, stream>>>(
      xzh, cw[0], cb[0], cw[1], cb[1], xch);

  // x_proj: (8192x512)bf16 @ (48x512)^T bf16 -> f32 (8192x48), both dirs
  gemm_mfma<<<dim3(64, 1, 2), 256, 0, stream>>>(
      xch, (size_t)8192 * 512, 512,
      w_xp[0], w_xp[1], 512,
      dbl, (size_t)8192 * 48, 48,
      8192, 48, 512, 0, nullptr, 0, 0);

  // dt: (8192x16[lda48]) @ (512x16)^T f32 -> softplus(+bias) -> bf16, both dirs
  gemm_bt<<<dim3(128, 8, 2), 256, 0, stream>>>(
      dbl, (size_t)8192 * 48, 48,
      dtw[0], dtw[1], 16,
      dtbh, (size_t)8192 * 512, 512,
      8192, 512, 16, 1, dtbias[0], dtbias[1], 1);

  scan_part1<<<dim3(2, NCHUNK, 4), 256, 0, stream>>>(
      xch, dtbh, dbl, alog[0], alog[1], aflag, Ac, Bc);
  scan_mid<<<dim3(128), 256, 0, stream>>>(Ac, Bc, HinB);
  scan_part2<<<dim3(2, NCHUNK, 4), 256, 0, stream>>>(
      xzh, xch, dtbh, dbl, alog[0], alog[1], dvec[0], dvec[1], aflag, HinB, yvh);

  // out_proj: (8192x512)bf16 @ (256x512)^T bf16 + x -> out, both dirs
  gemm_mfma<<<dim3(64, 2, 2), 256, 0, stream>>>(
      yvh, (size_t)8192 * 512, 512,
      w_out[0], w_out[1], 512,
      out, (size_t)256, 512,
      8192, 256, 512, 2, x, 256, 0);
}

// Round 20
// 196.215 us; speedup vs baseline: 1.0644x; 1.0644x over previous
//
#include <hip/hip_runtime.h>
#include <hip/hip_bf16.h>
#include <math.h>

#define NCHUNK 256
#define CLEN 16   // NCHUNK * CLEN == 4096

typedef __attribute__((ext_vector_type(8))) short short8;
typedef __attribute__((ext_vector_type(4))) float f32x4;

__device__ __forceinline__ void gload16(const void* g, void* l) {
  __builtin_amdgcn_global_load_lds(
      (const __attribute__((address_space(1))) void*)g,
      (__attribute__((address_space(3))) void*)l, 16, 0, 0);
}

__device__ __forceinline__ float bf2f(short s) {
  unsigned int u = ((unsigned int)(unsigned short)s) << 16;
  return __uint_as_float(u);
}
__device__ __forceinline__ short f2bf(float f) {
  __hip_bfloat16 h = __float2bfloat16(f);
  return *reinterpret_cast<short*>(&h);
}

// E^(n+1) for n=0..15 via log-depth product tree (14 muls, depth ~4)
__device__ __forceinline__ void pow_tree(float E, float g[16]) {
  g[0] = E;          g[1] = E * E;        g[2] = g[1] * E;     g[3] = g[1] * g[1];
  g[4] = g[3] * E;   g[5] = g[3] * g[1];  g[6] = g[5] * E;     g[7] = g[3] * g[3];
  g[8] = g[7] * E;   g[9] = g[7] * g[1];  g[10] = g[9] * E;    g[11] = g[7] * g[3];
  g[12] = g[11] * E; g[13] = g[11] * g[1]; g[14] = g[13] * E;  g[15] = g[7] * g[7];
}

// ---------------- weight cast: 6 fp32 tensors -> one contiguous bf16 buffer --
__global__ __launch_bounds__(256) void cast_weights(
    const float* __restrict__ a0, const float* __restrict__ a1,
    const float* __restrict__ a2, const float* __restrict__ a3,
    const float* __restrict__ a4, const float* __restrict__ a5,
    __hip_bfloat16* __restrict__ dst)
{
  int gid = blockIdx.x * 256 + threadIdx.x;
  if (gid >= 835584) return;
  int off = gid; const float* s;
  if (off < 262144) s = a0;
  else if ((off -= 262144) < 262144) s = a1;
  else if ((off -= 262144) < 131072) s = a2;
  else if ((off -= 131072) < 131072) s = a3;
  else if ((off -= 131072) < 24576) s = a4;
  else { off -= 24576; s = a5; }
  dst[gid] = __float2bfloat16(s[off]);
}

// ---------------- RMSNorm: both dirs in one pass (shared row + reduction) ----
__global__ __launch_bounds__(256) void rmsnorm_kernel(
    const float* __restrict__ x,
    const float* __restrict__ w_fw, const float* __restrict__ w_bw,
    __hip_bfloat16* __restrict__ xnh)
{
  int row = blockIdx.x;          // b*4096 + l
  int tid = threadIdx.x;
  float v = x[row * 256 + tid];
  float ss = v * v;
  #pragma unroll
  for (int m = 32; m; m >>= 1) ss += __shfl_xor(ss, m, 64);
  __shared__ float red[4];
  if ((tid & 63) == 0) red[tid >> 6] = ss;
  __syncthreads();
  float tot = red[0] + red[1] + red[2] + red[3];
  float sc = rsqrtf(tot / 256.f + 1e-5f);
  float vs = v * sc;
  xnh[(size_t)row * 256 + tid] = __float2bfloat16(vs * w_fw[tid]);
  xnh[((size_t)8192 + row) * 256 + tid] = __float2bfloat16(vs * w_bw[tid]);
}

// ---------------- bf16 MFMA GEMM, both dirs batched via blockIdx.z ----------
// C[M,N] = A[M,K] * B[N,K]^T ; obf: bf16 store; epi 2: + ep_mat[m*ep_ld+n]
__global__ __launch_bounds__(256) void gemm_mfma(
    const __hip_bfloat16* __restrict__ A, size_t aStr, int lda,
    const __hip_bfloat16* __restrict__ B0, const __hip_bfloat16* __restrict__ B1,
    int ldb,
    void* __restrict__ C, size_t cStr, int ldc,
    int M, int N, int K,
    int epi, const float* __restrict__ ep_mat, int ep_ld, int obf)
{
  __shared__ __align__(16) __hip_bfloat16 As[128 * 32];
  __shared__ __align__(16) __hip_bfloat16 Bs[128 * 32];
  int tid = threadIdx.x;
  int lane = tid & 63, wid = tid >> 6;
  int dir = blockIdx.z;
  const __hip_bfloat16* Ad = A + (size_t)dir * aStr;
  const __hip_bfloat16* Bd = dir ? B1 : B0;
  int m0 = blockIdx.x * 128, n0 = blockIdx.y * 128;
  int wr = wid & 1, wc = wid >> 1;

  f32x4 acc[4][4] = {};

  int lrow = lane >> 2;
  int lk8  = (lane & 3) * 8;

  for (int k0 = 0; k0 < K; k0 += 32) {
    __syncthreads();
    #pragma unroll
    for (int s = 0; s < 2; s++) {
      int r = wid * 2 + s;
      int arow = m0 + r * 16 + lrow;
      gload16(Ad + (size_t)arow * lda + k0 + lk8, &As[r * 512]);
      int brow = n0 + r * 16 + lrow;
      if (brow > N - 1) brow = N - 1;
      gload16(Bd + (size_t)brow * ldb + k0 + lk8, &Bs[r * 512]);
    }
    __syncthreads();

    short8 af[4], bfr[4];
    #pragma unroll
    for (int i = 0; i < 4; i++)
      af[i] = *(const short8*)&As[(wr * 64 + i * 16 + (lane & 15)) * 32 + (lane >> 4) * 8];
    #pragma unroll
    for (int j = 0; j < 4; j++)
      bfr[j] = *(const short8*)&Bs[(wc * 64 + j * 16 + (lane & 15)) * 32 + (lane >> 4) * 8];
    #pragma unroll
    for (int i = 0; i < 4; i++)
      #pragma unroll
      for (int j = 0; j < 4; j++)
        acc[i][j] = __builtin_amdgcn_mfma_f32_16x16x32_bf16(af[i], bfr[j], acc[i][j], 0, 0, 0);
  }

  int crow = (lane >> 4) * 4;
  int ccol = lane & 15;
  #pragma unroll
  for (int i = 0; i < 4; i++) {
    #pragma unroll
    for (int j = 0; j < 4; j++) {
      int nn = n0 + wc * 64 + j * 16 + ccol;
      if (nn < N) {
        #pragma unroll
        for (int q = 0; q < 4; q++) {
          int mm = m0 + wr * 64 + i * 16 + crow + q;
          float v = acc[i][j][q];
          if (obf) {
            ((__hip_bfloat16*)C)[(size_t)dir * cStr + (size_t)mm * ldc + nn] =
                __float2bfloat16(v);
          } else {
            if (epi == 2) v += ep_mat[(size_t)mm * ep_ld + nn];
            ((float*)C)[(size_t)dir * cStr + (size_t)mm * ldc + nn] = v;
          }
        }
      }
    }
  }
}

// ---------------- fp32 GEMM (dt path, K=16), dirs batched --------------------
// epi 1: softplus(acc + ep_vec[n]); obf 1: bf16 store
__global__ __launch_bounds__(256) void gemm_bt(
    const float* __restrict__ A, size_t aStr, int lda,
    const float* __restrict__ B0, const float* __restrict__ B1, int ldb,
    void* __restrict__ C, size_t cStr, int ldc,
    int M, int N, int K,
    int epi, const float* __restrict__ ev0, const float* __restrict__ ev1,
    int obf)
{
  __shared__ float As[16][64];
  __shared__ float Bs[16][64];
  int tid = threadIdx.x;
  int dir = blockIdx.z;
  const float* Ad = A + (size_t)dir * aStr;
  const float* Bd = dir ? B1 : B0;
  const float* ep_vec = dir ? ev1 : ev0;
  int tx = tid & 15, ty = tid >> 4;
  int m0 = blockIdx.x * 64, n0 = blockIdx.y * 64;
  int lr = tid >> 2;
  int lk = (tid & 3) << 2;
  float acc[4][4] = {};

  for (int k0 = 0; k0 < K; k0 += 16) {
    float4 av = *(const float4*)&Ad[(size_t)(m0 + lr) * lda + k0 + lk];
    float4 bv = make_float4(0.f, 0.f, 0.f, 0.f);
    if (n0 + lr < N) bv = *(const float4*)&Bd[(size_t)(n0 + lr) * ldb + k0 + lk];
    __syncthreads();
    As[lk + 0][lr] = av.x; As[lk + 1][lr] = av.y;
    As[lk + 2][lr] = av.z; As[lk + 3][lr] = av.w;
    Bs[lk + 0][lr] = bv.x; Bs[lk + 1][lr] = bv.y;
    Bs[lk + 2][lr] = bv.z; Bs[lk + 3][lr] = bv.w;
    __syncthreads();
    #pragma unroll
    for (int kk = 0; kk < 16; kk++) {
      float4 a4 = *(const float4*)&As[kk][ty << 2];
      float4 b4 = *(const float4*)&Bs[kk][tx << 2];
      float ar[4] = {a4.x, a4.y, a4.z, a4.w};
      float br[4] = {b4.x, b4.y, b4.z, b4.w};
      #pragma unroll
      for (int i = 0; i < 4; i++)
        #pragma unroll
        for (int j = 0; j < 4; j++)
          acc[i][j] = fmaf(ar[i], br[j], acc[i][j]);
    }
  }

  #pragma unroll
  for (int i = 0; i < 4; i++) {
    int m = m0 + (ty << 2) + i;
    #pragma unroll
    for (int j = 0; j < 4; j++) {
      int n = n0 + (tx << 2) + j;
      if (n < N) {
        float v = acc[i][j];
        if (epi == 1) {
          v += ep_vec[n];
          v = fmaxf(v, 0.f) + log1pf(__expf(-fabsf(v)));  // stable softplus
        }
        if (obf) ((__hip_bfloat16*)C)[(size_t)dir * cStr + (size_t)m * ldc + n] =
                     __float2bfloat16(v);
        else     ((float*)C)[(size_t)dir * cStr + (size_t)m * ldc + n] = v;
      }
    }
  }
}

// ---------------- Depthwise causal conv(4) + SiLU, 8 ch x 8 rows / thread ----
__global__ __launch_bounds__(256) void conv_silu_kernel(
    const __hip_bfloat16* __restrict__ xzh,
    const float* __restrict__ cw_fw, const float* __restrict__ cb_fw,
    const float* __restrict__ cw_bw, const float* __restrict__ cb_bw,
    __hip_bfloat16* __restrict__ xch)
{
  int dir = blockIdx.y;
  int gid = blockIdx.x * 256 + threadIdx.x;   // 64 dg-groups x 1024 row-groups
  int dg = (gid & 63) * 8;
  int rg = gid >> 6;           // 0..1023
  int b  = rg >> 9;            // batch
  int p0 = (rg & 511) * 8;     // 8-row group within sequence
  const float* cw = dir ? cw_bw : cw_fw;
  const float* cb = dir ? cb_bw : cb_fw;
  const __hip_bfloat16* xi = xzh + (size_t)dir * 8192 * 1024;

  float4 w4[8]; float bias[8];
  #pragma unroll
  for (int k = 0; k < 8; k++) {
    w4[k] = *(const float4*)&cw[(dg + k) * 4];
    bias[k] = cb[dg + k];
  }

  size_t rowbase = (size_t)(b * 4096) * 1024 + dg;
  int step = dir ? -1 : 1;
  int pstart = dir ? p0 + 7 : p0;

  short8 zero = {0, 0, 0, 0, 0, 0, 0, 0};
  short8 win0 = zero, win1 = zero, win2 = zero;
  {
    int pp = pstart - 3 * step;
    if (pp >= 0 && pp < 4096) win0 = *(const short8*)&xi[rowbase + (size_t)pp * 1024];
    pp = pstart - 2 * step;
    if (pp >= 0 && pp < 4096) win1 = *(const short8*)&xi[rowbase + (size_t)pp * 1024];
    pp = pstart - step;
    if (pp >= 0 && pp < 4096) win2 = *(const short8*)&xi[rowbase + (size_t)pp * 1024];
  }

  #pragma unroll
  for (int i = 0; i < 8; i++) {
    int prow = pstart + step * i;
    short8 cur = *(const short8*)&xi[rowbase + (size_t)prow * 1024];
    short8 o;
    #pragma unroll
    for (int k = 0; k < 8; k++) {
      float acc = bias[k];
      acc = fmaf(w4[k].x, bf2f(win0[k]), acc);
      acc = fmaf(w4[k].y, bf2f(win1[k]), acc);
      acc = fmaf(w4[k].z, bf2f(win2[k]), acc);
      acc = fmaf(w4[k].w, bf2f(cur[k]),  acc);
      float s = acc / (1.f + __expf(-acc));
      o[k] = f2bf(s);
    }
    *(short8*)&xch[((size_t)dir * 8192 + b * 4096 + prow) * 512 + dg] = o;
    win0 = win1; win1 = win2; win2 = cur;
  }
}

// ---------------- Chunked selective scan (dt precomputed, bf16 inputs) ------
// Fast path: if a[n] == -(n+1) (the model's A_log structure, verified at
// runtime), gates are E^(n+1) with E = exp(dt*a0): 1 exp + 14 muls instead
// of 16 exps (trans pipe relief). Generic fallback otherwise.
// Phase 1: per-chunk (Ac, Bc) bf16. grid (2, NCHUNK, 4), block 256
__global__ __launch_bounds__(256) void scan_part1(
    const __hip_bfloat16* __restrict__ xch, const __hip_bfloat16* __restrict__ dtbh,
    const float* __restrict__ dbl,
    const float* __restrict__ Alog_fw, const float* __restrict__ Alog_bw,
    __hip_bfloat16* __restrict__ Ac, __hip_bfloat16* __restrict__ Bc)
{
  int tid = threadIdx.x;
  int d = blockIdx.x * 256 + tid;
  int c = blockIdx.y, bd = blockIdx.z, dir = bd >> 1;
  const float* Alog = dir ? Alog_bw : Alog_fw;

  float a[16], h[16];
  #pragma unroll
  for (int n = 0; n < 16; n++) {
    a[n] = -__expf(Alog[d * 16 + n]);
    h[n] = 0.f;
  }
  bool fast = true;
  #pragma unroll
  for (int n = 0; n < 16; n++)
    fast = fast && (fabsf(a[n] + (float)(n + 1)) < 1e-4f * (float)(n + 1));

  int base = bd * 4096;
  int stepw = dir ? -1 : 1;
  int t0 = c * CLEN;
  int r = base + (dir ? 4095 - t0 : t0);

  float dtv = __bfloat162float(dtbh[(size_t)r * 512 + d]);
  float uv  = __bfloat162float(xch[(size_t)r * 512 + d]);
  float sdt = 0.f;

  if (fast) {
    for (int i = 0; i < CLEN; i++) {
      const float* row = dbl + (size_t)r * 48 + 16;
      float dt_c = dtv, u_c = uv;
      if (i < CLEN - 1) {
        dtv = __bfloat162float(dtbh[(size_t)(r + stepw) * 512 + d]);
        uv  = __bfloat162float(xch[(size_t)(r + stepw) * 512 + d]);
      }
      sdt += dt_c;
      float dtu = dt_c * u_c;
      float g[16];
      pow_tree(__expf(dt_c * a[0]), g);
      #pragma unroll
      for (int n = 0; n < 16; n++)
        h[n] = fmaf(g[n], h[n], dtu * row[n]);
      r += stepw;
    }
  } else {
    for (int i = 0; i < CLEN; i++) {
      const float* row = dbl + (size_t)r * 48 + 16;
      float dt_c = dtv, u_c = uv;
      if (i < CLEN - 1) {
        dtv = __bfloat162float(dtbh[(size_t)(r + stepw) * 512 + d]);
        uv  = __bfloat162float(xch[(size_t)(r + stepw) * 512 + d]);
      }
      sdt += dt_c;
      float dtu = dt_c * u_c;
      #pragma unroll
      for (int n = 0; n < 16; n++) {
        float g = __expf(dt_c * a[n]);
        h[n] = fmaf(g, h[n], dtu * row[n]);
      }
      r += stepw;
    }
  }

  size_t ob = (((size_t)bd * NCHUNK + c) * 512 + d) * 16;
  float A16[16];
  if (fast) {
    pow_tree(__expf(sdt * a[0]), A16);
  } else {
    #pragma unroll
    for (int n = 0; n < 16; n++) A16[n] = __expf(a[n] * sdt);
  }
  short8 av0, av1, bv0, bv1;
  #pragma unroll
  for (int n = 0; n < 8; n++) {
    av0[n] = f2bf(A16[n]);
    av1[n] = f2bf(A16[8 + n]);
    bv0[n] = f2bf(h[n]);
    bv1[n] = f2bf(h[8 + n]);
  }
  *(short8*)&Ac[ob]     = av0;
  *(short8*)&Ac[ob + 8] = av1;
  *(short8*)&Bc[ob]     = bv0;
  *(short8*)&Bc[ob + 8] = bv1;
}

// Phase 2: sequential composition over chunks; bf16 in/out, fp32 accum.
__global__ __launch_bounds__(256) void scan_mid(
    const __hip_bfloat16* __restrict__ Ac, const __hip_bfloat16* __restrict__ Bc,
    __hip_bfloat16* __restrict__ HinB)
{
  int gid = blockIdx.x * 256 + threadIdx.x;   // 0..32767
  int bd = gid >> 13, pos = gid & 8191;
  size_t idx = (size_t)bd * NCHUNK * 8192 + pos;
  float h = 0.f;
  float av = __bfloat162float(Ac[idx]), bv = __bfloat162float(Bc[idx]);
  for (int c = 0; c < NCHUNK; c++) {
    float a0 = av, b0 = bv;
    if (c < NCHUNK - 1) {
      av = __bfloat162float(Ac[idx + 8192]);
      bv = __bfloat162float(Bc[idx + 8192]);
    }
    HinB[idx] = __float2bfloat16(h);
    h = fmaf(a0, h, b0);
    idx += 8192;
  }
}

// Phase 3: local rescan from Hin, emit y (bf16). grid (2, NCHUNK, 4)
__global__ __launch_bounds__(256) void scan_part2(
    const __hip_bfloat16* __restrict__ xzh, const __hip_bfloat16* __restrict__ xch,
    const __hip_bfloat16* __restrict__ dtbh, const float* __restrict__ dbl,
    const float* __restrict__ Alog_fw, const float* __restrict__ Alog_bw,
    const float* __restrict__ Dp_fw, const float* __restrict__ Dp_bw,
    const __hip_bfloat16* __restrict__ HinB, __hip_bfloat16* __restrict__ yvh)
{
  int tid = threadIdx.x;
  int d = blockIdx.x * 256 + tid;
  int c = blockIdx.y, bd = blockIdx.z, dir = bd >> 1;
  const float* Alog = dir ? Alog_bw : Alog_fw;
  float Dd = (dir ? Dp_bw : Dp_fw)[d];

  float a[16], h[16];
  size_t ob = (((size_t)bd * NCHUNK + c) * 512 + d) * 16;
  #pragma unroll
  for (int n = 0; n < 16; n++) {
    a[n] = -__expf(Alog[d * 16 + n]);
    h[n] = __bfloat162float(HinB[ob + n]);
  }
  bool fast = true;
  #pragma unroll
  for (int n = 0; n < 16; n++)
    fast = fast && (fabsf(a[n] + (float)(n + 1)) < 1e-4f * (float)(n + 1));

  int base = bd * 4096;
  int stepw = dir ? -1 : 1;
  int t0 = c * CLEN;
  int r = base + (dir ? 4095 - t0 : t0);

  float dtv = __bfloat162float(dtbh[(size_t)r * 512 + d]);
  float uv  = __bfloat162float(xch[(size_t)r * 512 + d]);
  float zv  = __bfloat162float(xzh[(size_t)r * 1024 + 512 + d]);

  if (fast) {
    for (int i = 0; i < CLEN; i++) {
      const float* row = dbl + (size_t)r * 48 + 16;
      float dt_c = dtv, u_c = uv, z_c = zv;
      int rc = r;
      if (i < CLEN - 1) {
        dtv = __bfloat162float(dtbh[(size_t)(r + stepw) * 512 + d]);
        uv  = __bfloat162float(xch[(size_t)(r + stepw) * 512 + d]);
        zv  = __bfloat162float(xzh[(size_t)(r + stepw) * 1024 + 512 + d]);
      }
      float dtu = dt_c * u_c;
      float g[16];
      pow_tree(__expf(dt_c * a[0]), g);
      float y = 0.f;
      #pragma unroll
      for (int n = 0; n < 16; n++) {
        h[n] = fmaf(g[n], h[n], dtu * row[n]);
        y = fmaf(h[n], row[16 + n], y);
      }
      float sz = z_c / (1.f + __expf(-z_c));
      yvh[(size_t)rc * 512 + d] = __float2bfloat16((y + Dd * u_c) * sz);
      r += stepw;
    }
  } else {
    for (int i = 0; i < CLEN; i++) {
      const float* row = dbl + (size_t)r * 48 + 16;
      float dt_c = dtv, u_c = uv, z_c = zv;
      int rc = r;
      if (i < CLEN - 1) {
        dtv = __bfloat162float(dtbh[(size_t)(r + stepw) * 512 + d]);
        uv  = __bfloat162float(xch[(size_t)(r + stepw) * 512 + d]);
        zv  = __bfloat162float(xzh[(size_t)(r + stepw) * 1024 + 512 + d]);
      }
      float dtu = dt_c * u_c;
      float y = 0.f;
      #pragma unroll
      for (int n = 0; n < 16; n++) {
        float g = __expf(dt_c * a[n]);
        h[n] = fmaf(g, h[n], dtu * row[n]);
        y = fmaf(h[n], row[16 + n], y);
      }
      float sz = z_c / (1.f + __expf(-z_c));
      yvh[(size_t)rc * 512 + d] = __float2bfloat16((y + Dd * u_c) * sz);
      r += stepw;
    }
  }
}

extern "C" void kernel_launch(void* const* d_in, const int* in_sizes, int n_in,
                              void* d_out, int out_size, void* d_ws, size_t ws_size,
                              hipStream_t stream)
{
  const float* x = (const float*)d_in[0];
  const float* nw[2]     = {(const float*)d_in[1],  (const float*)d_in[11]};
  const float* inp[2]    = {(const float*)d_in[2],  (const float*)d_in[12]};
  const float* cw[2]     = {(const float*)d_in[3],  (const float*)d_in[13]};
  const float* cb[2]     = {(const float*)d_in[4],  (const float*)d_in[14]};
  const float* xp[2]     = {(const float*)d_in[5],  (const float*)d_in[15]};
  const float* dtw[2]    = {(const float*)d_in[6],  (const float*)d_in[16]};
  const float* dtbias[2] = {(const float*)d_in[7],  (const float*)d_in[17]};
  const float* alog[2]   = {(const float*)d_in[8],  (const float*)d_in[18]};
  const float* dvec[2]   = {(const float*)d_in[9],  (const float*)d_in[19]};
  const float* outp[2]   = {(const float*)d_in[10], (const float*)d_in[20]};

  float* ws = (float*)d_ws;
  size_t F = 0;
  __hip_bfloat16* xzh = (__hip_bfloat16*)(ws + F);      // bf16 2*8192*1024
  F += (size_t)2 * 8192 * 512;
  __hip_bfloat16* xch = (__hip_bfloat16*)(ws + F);      // bf16 2*8192*512
  F += (size_t)2 * 8192 * 256;
  float* dbl = ws + F;  F += (size_t)2 * 8192 * 48;
  __hip_bfloat16* dtbh = (__hip_bfloat16*)(ws + F);     // bf16 2*8192*512
  F += (size_t)2 * 8192 * 256;
  __hip_bfloat16* Ac = (__hip_bfloat16*)(ws + F);       // bf16 4*NCHUNK*8192
  F += (size_t)2 * NCHUNK * 8192;
  __hip_bfloat16* Bc = (__hip_bfloat16*)(ws + F);       // bf16 4*NCHUNK*8192
  F += (size_t)2 * NCHUNK * 8192;
  __hip_bfloat16* yvh = (__hip_bfloat16*)(ws + F);      // bf16 2*8192*512
  F += (size_t)2 * 8192 * 256;
  __hip_bfloat16* xnh = (__hip_bfloat16*)(ws + F);      // bf16 2*8192*256
  F += (size_t)2 * 8192 * 128;
  __hip_bfloat16* wb  = (__hip_bfloat16*)(ws + F);      // bf16 835584
  F += 835584 / 2;
  __hip_bfloat16* HinB = (__hip_bfloat16*)d_out;  // 8.39M bf16 = d_out exactly
  float* out = (float*)d_out;

  __hip_bfloat16* w_in[2]  = {wb,            wb + 262144};
  __hip_bfloat16* w_out[2] = {wb + 524288,   wb + 655360};
  __hip_bfloat16* w_xp[2]  = {wb + 786432,   wb + 811008};

  cast_weights<<<dim3(3264), 256, 0, stream>>>(
      inp[0], inp[1], outp[0], outp[1], xp[0], xp[1], wb);

  rmsnorm_kernel<<<dim3(8192), 256, 0, stream>>>(x, nw[0], nw[1], xnh);

  // in_proj: (8192x256)bf16 @ (1024x256)^T bf16 -> bf16 (8192x1024), both dirs
  gemm_mfma<<<dim3(64, 8, 2), 256, 0, stream>>>(
      xnh, (size_t)8192 * 256, 256,
      w_in[0], w_in[1], 256,
      xzh, (size_t)8192 * 1024, 1024,
      8192, 1024, 256, 0, nullptr, 0, 1);

  conv_silu_kernel<<<dim3(256, 2), 256, 0, stream>>>(
      xzh, cw[0], cb[0], cw[1], cb[1], xch);

  // x_proj: (8192x512)bf16 @ (48x512)^T bf16 -> f32 (8192x48), both dirs
  gemm_mfma<<<dim3(64, 1, 2), 256, 0, stream>>>(
      xch, (size_t)8192 * 512, 512,
      w_xp[0], w_xp[1], 512,
      dbl, (size_t)8192 * 48, 48,
      8192, 48, 512, 0, nullptr, 0, 0);

  // dt: (8192x16[lda48]) @ (512x16)^T f32 -> softplus(+bias) -> bf16, both dirs
  gemm_bt<<<dim3(128, 8, 2), 256, 0, stream>>>(
      dbl, (size_t)8192 * 48, 48,
      dtw[0], dtw[1], 16,
      dtbh, (size_t)8192 * 512, 512,
      8192, 512, 16, 1, dtbias[0], dtbias[1], 1);

  scan_part1<<<dim3(2, NCHUNK, 4), 256, 0, stream>>>(
      xch, dtbh, dbl, alog[0], alog[1], Ac, Bc);
  scan_mid<<<dim3(128), 256, 0, stream>>>(Ac, Bc, HinB);
  scan_part2<<<dim3(2, NCHUNK, 4), 256, 0, stream>>>(
      xzh, xch, dtbh, dbl, alog[0], alog[1], dvec[0], dvec[1], HinB, yvh);

  // out_proj: (8192x512)bf16 @ (256x512)^T bf16 + x -> out, both dirs
  gemm_mfma<<<dim3(64, 2, 2), 256, 0, stream>>>(
      yvh, (size_t)8192 * 512, 512,
      w_out[0], w_out[1], 512,
      out, (size_t)256, 512,
      8192, 256, 512, 2, x, 256, 0);
}

// Round 21
// 177.533 us; speedup vs baseline: 1.1765x; 1.1052x over previous
//
#include <hip/hip_runtime.h>
#include <hip/hip_bf16.h>
#include <math.h>

#define NCHUNK 256
#define CLEN 16   // NCHUNK * CLEN == 4096

typedef __attribute__((ext_vector_type(8))) short short8;
typedef __attribute__((ext_vector_type(4))) float f32x4;

__device__ __forceinline__ void gload16(const void* g, void* l) {
  __builtin_amdgcn_global_load_lds(
      (const __attribute__((address_space(1))) void*)g,
      (__attribute__((address_space(3))) void*)l, 16, 0, 0);
}

__device__ __forceinline__ float bf2f(short s) {
  unsigned int u = ((unsigned int)(unsigned short)s) << 16;
  return __uint_as_float(u);
}
__device__ __forceinline__ short f2bf(float f) {
  __hip_bfloat16 h = __float2bfloat16(f);
  return *reinterpret_cast<short*>(&h);
}

// E^(n+1) for n=0..15 via log-depth product tree (14 muls, depth ~4)
__device__ __forceinline__ void pow_tree(float E, float g[16]) {
  g[0] = E;          g[1] = E * E;        g[2] = g[1] * E;     g[3] = g[1] * g[1];
  g[4] = g[3] * E;   g[5] = g[3] * g[1];  g[6] = g[5] * E;     g[7] = g[3] * g[3];
  g[8] = g[7] * E;   g[9] = g[7] * g[1];  g[10] = g[9] * E;    g[11] = g[7] * g[3];
  g[12] = g[11] * E; g[13] = g[11] * g[1]; g[14] = g[13] * E;  g[15] = g[7] * g[7];
}

// ---------------- weight cast: 6 fp32 tensors -> one contiguous bf16 buffer --
__global__ __launch_bounds__(256) void cast_weights(
    const float* __restrict__ a0, const float* __restrict__ a1,
    const float* __restrict__ a2, const float* __restrict__ a3,
    const float* __restrict__ a4, const float* __restrict__ a5,
    __hip_bfloat16* __restrict__ dst)
{
  int gid = blockIdx.x * 256 + threadIdx.x;
  if (gid >= 835584) return;
  int off = gid; const float* s;
  if (off < 262144) s = a0;
  else if ((off -= 262144) < 262144) s = a1;
  else if ((off -= 262144) < 131072) s = a2;
  else if ((off -= 131072) < 131072) s = a3;
  else if ((off -= 131072) < 24576) s = a4;
  else { off -= 24576; s = a5; }
  dst[gid] = __float2bfloat16(s[off]);
}

// ---------------- RMSNorm: both dirs in one pass (shared row + reduction) ----
__global__ __launch_bounds__(256) void rmsnorm_kernel(
    const float* __restrict__ x,
    const float* __restrict__ w_fw, const float* __restrict__ w_bw,
    __hip_bfloat16* __restrict__ xnh)
{
  int row = blockIdx.x;          // b*4096 + l
  int tid = threadIdx.x;
  float v = x[row * 256 + tid];
  float ss = v * v;
  #pragma unroll
  for (int m = 32; m; m >>= 1) ss += __shfl_xor(ss, m, 64);
  __shared__ float red[4];
  if ((tid & 63) == 0) red[tid >> 6] = ss;
  __syncthreads();
  float tot = red[0] + red[1] + red[2] + red[3];
  float sc = rsqrtf(tot / 256.f + 1e-5f);
  float vs = v * sc;
  xnh[(size_t)row * 256 + tid] = __float2bfloat16(vs * w_fw[tid]);
  xnh[((size_t)8192 + row) * 256 + tid] = __float2bfloat16(vs * w_bw[tid]);
}

// ---------------- bf16 MFMA GEMM, both dirs batched via blockIdx.z ----------
// C[M,N] = A[M,K] * B[N,K]^T ; obf: bf16 store; epi 2: + ep_mat[m*ep_ld+n]
__global__ __launch_bounds__(256) void gemm_mfma(
    const __hip_bfloat16* __restrict__ A, size_t aStr, int lda,
    const __hip_bfloat16* __restrict__ B0, const __hip_bfloat16* __restrict__ B1,
    int ldb,
    void* __restrict__ C, size_t cStr, int ldc,
    int M, int N, int K,
    int epi, const float* __restrict__ ep_mat, int ep_ld, int obf)
{
  __shared__ __align__(16) __hip_bfloat16 As[128 * 32];
  __shared__ __align__(16) __hip_bfloat16 Bs[128 * 32];
  int tid = threadIdx.x;
  int lane = tid & 63, wid = tid >> 6;
  int dir = blockIdx.z;
  const __hip_bfloat16* Ad = A + (size_t)dir * aStr;
  const __hip_bfloat16* Bd = dir ? B1 : B0;
  int m0 = blockIdx.x * 128, n0 = blockIdx.y * 128;
  int wr = wid & 1, wc = wid >> 1;

  f32x4 acc[4][4] = {};

  int lrow = lane >> 2;
  int lk8  = (lane & 3) * 8;

  for (int k0 = 0; k0 < K; k0 += 32) {
    __syncthreads();
    #pragma unroll
    for (int s = 0; s < 2; s++) {
      int r = wid * 2 + s;
      int arow = m0 + r * 16 + lrow;
      gload16(Ad + (size_t)arow * lda + k0 + lk8, &As[r * 512]);
      int brow = n0 + r * 16 + lrow;
      if (brow > N - 1) brow = N - 1;
      gload16(Bd + (size_t)brow * ldb + k0 + lk8, &Bs[r * 512]);
    }
    __syncthreads();

    short8 af[4], bfr[4];
    #pragma unroll
    for (int i = 0; i < 4; i++)
      af[i] = *(const short8*)&As[(wr * 64 + i * 16 + (lane & 15)) * 32 + (lane >> 4) * 8];
    #pragma unroll
    for (int j = 0; j < 4; j++)
      bfr[j] = *(const short8*)&Bs[(wc * 64 + j * 16 + (lane & 15)) * 32 + (lane >> 4) * 8];
    #pragma unroll
    for (int i = 0; i < 4; i++)
      #pragma unroll
      for (int j = 0; j < 4; j++)
        acc[i][j] = __builtin_amdgcn_mfma_f32_16x16x32_bf16(af[i], bfr[j], acc[i][j], 0, 0, 0);
  }

  int crow = (lane >> 4) * 4;
  int ccol = lane & 15;
  #pragma unroll
  for (int i = 0; i < 4; i++) {
    #pragma unroll
    for (int j = 0; j < 4; j++) {
      int nn = n0 + wc * 64 + j * 16 + ccol;
      if (nn < N) {
        #pragma unroll
        for (int q = 0; q < 4; q++) {
          int mm = m0 + wr * 64 + i * 16 + crow + q;
          float v = acc[i][j][q];
          if (obf) {
            ((__hip_bfloat16*)C)[(size_t)dir * cStr + (size_t)mm * ldc + nn] =
                __float2bfloat16(v);
          } else {
            if (epi == 2) v += ep_mat[(size_t)mm * ep_ld + nn];
            ((float*)C)[(size_t)dir * cStr + (size_t)mm * ldc + nn] = v;
          }
        }
      }
    }
  }
}

// ---------------- fp32 GEMM (dt path, K=16), dirs batched --------------------
// epi 1: softplus via native __logf (log1pf is a slow libm sequence);
// obf 1: bf16 store
__global__ __launch_bounds__(256) void gemm_bt(
    const float* __restrict__ A, size_t aStr, int lda,
    const float* __restrict__ B0, const float* __restrict__ B1, int ldb,
    void* __restrict__ C, size_t cStr, int ldc,
    int M, int N, int K,
    int epi, const float* __restrict__ ev0, const float* __restrict__ ev1,
    int obf)
{
  __shared__ float As[16][64];
  __shared__ float Bs[16][64];
  int tid = threadIdx.x;
  int dir = blockIdx.z;
  const float* Ad = A + (size_t)dir * aStr;
  const float* Bd = dir ? B1 : B0;
  const float* ep_vec = dir ? ev1 : ev0;
  int tx = tid & 15, ty = tid >> 4;
  int m0 = blockIdx.x * 64, n0 = blockIdx.y * 64;
  int lr = tid >> 2;
  int lk = (tid & 3) << 2;
  float acc[4][4] = {};

  for (int k0 = 0; k0 < K; k0 += 16) {
    float4 av = *(const float4*)&Ad[(size_t)(m0 + lr) * lda + k0 + lk];
    float4 bv = make_float4(0.f, 0.f, 0.f, 0.f);
    if (n0 + lr < N) bv = *(const float4*)&Bd[(size_t)(n0 + lr) * ldb + k0 + lk];
    __syncthreads();
    As[lk + 0][lr] = av.x; As[lk + 1][lr] = av.y;
    As[lk + 2][lr] = av.z; As[lk + 3][lr] = av.w;
    Bs[lk + 0][lr] = bv.x; Bs[lk + 1][lr] = bv.y;
    Bs[lk + 2][lr] = bv.z; Bs[lk + 3][lr] = bv.w;
    __syncthreads();
    #pragma unroll
    for (int kk = 0; kk < 16; kk++) {
      float4 a4 = *(const float4*)&As[kk][ty << 2];
      float4 b4 = *(const float4*)&Bs[kk][tx << 2];
      float ar[4] = {a4.x, a4.y, a4.z, a4.w};
      float br[4] = {b4.x, b4.y, b4.z, b4.w};
      #pragma unroll
      for (int i = 0; i < 4; i++)
        #pragma unroll
        for (int j = 0; j < 4; j++)
          acc[i][j] = fmaf(ar[i], br[j], acc[i][j]);
    }
  }

  #pragma unroll
  for (int i = 0; i < 4; i++) {
    int m = m0 + (ty << 2) + i;
    #pragma unroll
    for (int j = 0; j < 4; j++) {
      int n = n0 + (tx << 2) + j;
      if (n < N) {
        float v = acc[i][j];
        if (epi == 1) {
          v += ep_vec[n];
          // stable softplus with native log: max(v,0) + log(1 + e^-|v|)
          v = fmaxf(v, 0.f) + __logf(1.f + __expf(-fabsf(v)));
        }
        if (obf) ((__hip_bfloat16*)C)[(size_t)dir * cStr + (size_t)m * ldc + n] =
                     __float2bfloat16(v);
        else     ((float*)C)[(size_t)dir * cStr + (size_t)m * ldc + n] = v;
      }
    }
  }
}

// ---------------- Depthwise causal conv(4) + SiLU, 8 ch x 8 rows / thread ----
__global__ __launch_bounds__(256) void conv_silu_kernel(
    const __hip_bfloat16* __restrict__ xzh,
    const float* __restrict__ cw_fw, const float* __restrict__ cb_fw,
    const float* __restrict__ cw_bw, const float* __restrict__ cb_bw,
    __hip_bfloat16* __restrict__ xch)
{
  int dir = blockIdx.y;
  int gid = blockIdx.x * 256 + threadIdx.x;   // 64 dg-groups x 1024 row-groups
  int dg = (gid & 63) * 8;
  int rg = gid >> 6;           // 0..1023
  int b  = rg >> 9;            // batch
  int p0 = (rg & 511) * 8;     // 8-row group within sequence
  const float* cw = dir ? cw_bw : cw_fw;
  const float* cb = dir ? cb_bw : cb_fw;
  const __hip_bfloat16* xi = xzh + (size_t)dir * 8192 * 1024;

  float4 w4[8]; float bias[8];
  #pragma unroll
  for (int k = 0; k < 8; k++) {
    w4[k] = *(const float4*)&cw[(dg + k) * 4];
    bias[k] = cb[dg + k];
  }

  size_t rowbase = (size_t)(b * 4096) * 1024 + dg;
  int step = dir ? -1 : 1;
  int pstart = dir ? p0 + 7 : p0;

  short8 zero = {0, 0, 0, 0, 0, 0, 0, 0};
  short8 win0 = zero, win1 = zero, win2 = zero;
  {
    int pp = pstart - 3 * step;
    if (pp >= 0 && pp < 4096) win0 = *(const short8*)&xi[rowbase + (size_t)pp * 1024];
    pp = pstart - 2 * step;
    if (pp >= 0 && pp < 4096) win1 = *(const short8*)&xi[rowbase + (size_t)pp * 1024];
    pp = pstart - step;
    if (pp >= 0 && pp < 4096) win2 = *(const short8*)&xi[rowbase + (size_t)pp * 1024];
  }

  #pragma unroll
  for (int i = 0; i < 8; i++) {
    int prow = pstart + step * i;
    short8 cur = *(const short8*)&xi[rowbase + (size_t)prow * 1024];
    short8 o;
    #pragma unroll
    for (int k = 0; k < 8; k++) {
      float acc = bias[k];
      acc = fmaf(w4[k].x, bf2f(win0[k]), acc);
      acc = fmaf(w4[k].y, bf2f(win1[k]), acc);
      acc = fmaf(w4[k].z, bf2f(win2[k]), acc);
      acc = fmaf(w4[k].w, bf2f(cur[k]),  acc);
      float s = acc / (1.f + __expf(-acc));
      o[k] = f2bf(s);
    }
    *(short8*)&xch[((size_t)dir * 8192 + b * 4096 + prow) * 512 + dg] = o;
    win0 = win1; win1 = win2; win2 = cur;
  }
}

// ---------------- Chunked selective scan (dt precomputed, bf16 inputs) ------
// Fast path: if a[n] == -(n+1) (the model's A_log structure, verified at
// runtime), gates are E^(n+1) with E = exp(dt*a0): 1 exp + 14 muls instead
// of 16 exps (trans pipe relief). Generic fallback otherwise.
// Phase 1: per-chunk (Ac, Bc) bf16. grid (2, NCHUNK, 4), block 256
__global__ __launch_bounds__(256) void scan_part1(
    const __hip_bfloat16* __restrict__ xch, const __hip_bfloat16* __restrict__ dtbh,
    const float* __restrict__ dbl,
    const float* __restrict__ Alog_fw, const float* __restrict__ Alog_bw,
    __hip_bfloat16* __restrict__ Ac, __hip_bfloat16* __restrict__ Bc)
{
  int tid = threadIdx.x;
  int d = blockIdx.x * 256 + tid;
  int c = blockIdx.y, bd = blockIdx.z, dir = bd >> 1;
  const float* Alog = dir ? Alog_bw : Alog_fw;

  float a[16], h[16];
  #pragma unroll
  for (int n = 0; n < 16; n++) {
    a[n] = -__expf(Alog[d * 16 + n]);
    h[n] = 0.f;
  }
  bool fast = true;
  #pragma unroll
  for (int n = 0; n < 16; n++)
    fast = fast && (fabsf(a[n] + (float)(n + 1)) < 1e-4f * (float)(n + 1));

  int base = bd * 4096;
  int stepw = dir ? -1 : 1;
  int t0 = c * CLEN;
  int r = base + (dir ? 4095 - t0 : t0);

  float dtv = __bfloat162float(dtbh[(size_t)r * 512 + d]);
  float uv  = __bfloat162float(xch[(size_t)r * 512 + d]);
  float sdt = 0.f;

  if (fast) {
    for (int i = 0; i < CLEN; i++) {
      const float* row = dbl + (size_t)r * 48 + 16;
      float dt_c = dtv, u_c = uv;
      if (i < CLEN - 1) {
        dtv = __bfloat162float(dtbh[(size_t)(r + stepw) * 512 + d]);
        uv  = __bfloat162float(xch[(size_t)(r + stepw) * 512 + d]);
      }
      sdt += dt_c;
      float dtu = dt_c * u_c;
      float g[16];
      pow_tree(__expf(dt_c * a[0]), g);
      #pragma unroll
      for (int n = 0; n < 16; n++)
        h[n] = fmaf(g[n], h[n], dtu * row[n]);
      r += stepw;
    }
  } else {
    for (int i = 0; i < CLEN; i++) {
      const float* row = dbl + (size_t)r * 48 + 16;
      float dt_c = dtv, u_c = uv;
      if (i < CLEN - 1) {
        dtv = __bfloat162float(dtbh[(size_t)(r + stepw) * 512 + d]);
        uv  = __bfloat162float(xch[(size_t)(r + stepw) * 512 + d]);
      }
      sdt += dt_c;
      float dtu = dt_c * u_c;
      #pragma unroll
      for (int n = 0; n < 16; n++) {
        float g = __expf(dt_c * a[n]);
        h[n] = fmaf(g, h[n], dtu * row[n]);
      }
      r += stepw;
    }
  }

  size_t ob = (((size_t)bd * NCHUNK + c) * 512 + d) * 16;
  float A16[16];
  if (fast) {
    pow_tree(__expf(sdt * a[0]), A16);
  } else {
    #pragma unroll
    for (int n = 0; n < 16; n++) A16[n] = __expf(a[n] * sdt);
  }
  short8 av0, av1, bv0, bv1;
  #pragma unroll
  for (int n = 0; n < 8; n++) {
    av0[n] = f2bf(A16[n]);
    av1[n] = f2bf(A16[8 + n]);
    bv0[n] = f2bf(h[n]);
    bv1[n] = f2bf(h[8 + n]);
  }
  *(short8*)&Ac[ob]     = av0;
  *(short8*)&Ac[ob + 8] = av1;
  *(short8*)&Bc[ob]     = bv0;
  *(short8*)&Bc[ob + 8] = bv1;
}

// Phase 2: sequential composition over chunks; bf16 in/out, fp32 accum.
__global__ __launch_bounds__(256) void scan_mid(
    const __hip_bfloat16* __restrict__ Ac, const __hip_bfloat16* __restrict__ Bc,
    __hip_bfloat16* __restrict__ HinB)
{
  int gid = blockIdx.x * 256 + threadIdx.x;   // 0..32767
  int bd = gid >> 13, pos = gid & 8191;
  size_t idx = (size_t)bd * NCHUNK * 8192 + pos;
  float h = 0.f;
  float av = __bfloat162float(Ac[idx]), bv = __bfloat162float(Bc[idx]);
  for (int c = 0; c < NCHUNK; c++) {
    float a0 = av, b0 = bv;
    if (c < NCHUNK - 1) {
      av = __bfloat162float(Ac[idx + 8192]);
      bv = __bfloat162float(Bc[idx + 8192]);
    }
    HinB[idx] = __float2bfloat16(h);
    h = fmaf(a0, h, b0);
    idx += 8192;
  }
}

// Phase 3: local rescan from Hin, emit y (bf16). grid (2, NCHUNK, 4)
__global__ __launch_bounds__(256) void scan_part2(
    const __hip_bfloat16* __restrict__ xzh, const __hip_bfloat16* __restrict__ xch,
    const __hip_bfloat16* __restrict__ dtbh, const float* __restrict__ dbl,
    const float* __restrict__ Alog_fw, const float* __restrict__ Alog_bw,
    const float* __restrict__ Dp_fw, const float* __restrict__ Dp_bw,
    const __hip_bfloat16* __restrict__ HinB, __hip_bfloat16* __restrict__ yvh)
{
  int tid = threadIdx.x;
  int d = blockIdx.x * 256 + tid;
  int c = blockIdx.y, bd = blockIdx.z, dir = bd >> 1;
  const float* Alog = dir ? Alog_bw : Alog_fw;
  float Dd = (dir ? Dp_bw : Dp_fw)[d];

  float a[16], h[16];
  size_t ob = (((size_t)bd * NCHUNK + c) * 512 + d) * 16;
  #pragma unroll
  for (int n = 0; n < 16; n++) {
    a[n] = -__expf(Alog[d * 16 + n]);
    h[n] = __bfloat162float(HinB[ob + n]);
  }
  bool fast = true;
  #pragma unroll
  for (int n = 0; n < 16; n++)
    fast = fast && (fabsf(a[n] + (float)(n + 1)) < 1e-4f * (float)(n + 1));

  int base = bd * 4096;
  int stepw = dir ? -1 : 1;
  int t0 = c * CLEN;
  int r = base + (dir ? 4095 - t0 : t0);

  float dtv = __bfloat162float(dtbh[(size_t)r * 512 + d]);
  float uv  = __bfloat162float(xch[(size_t)r * 512 + d]);
  float zv  = __bfloat162float(xzh[(size_t)r * 1024 + 512 + d]);

  if (fast) {
    for (int i = 0; i < CLEN; i++) {
      const float* row = dbl + (size_t)r * 48 + 16;
      float dt_c = dtv, u_c = uv, z_c = zv;
      int rc = r;
      if (i < CLEN - 1) {
        dtv = __bfloat162float(dtbh[(size_t)(r + stepw) * 512 + d]);
        uv  = __bfloat162float(xch[(size_t)(r + stepw) * 512 + d]);
        zv  = __bfloat162float(xzh[(size_t)(r + stepw) * 1024 + 512 + d]);
      }
      float dtu = dt_c * u_c;
      float g[16];
      pow_tree(__expf(dt_c * a[0]), g);
      float y = 0.f;
      #pragma unroll
      for (int n = 0; n < 16; n++) {
        h[n] = fmaf(g[n], h[n], dtu * row[n]);
        y = fmaf(h[n], row[16 + n], y);
      }
      float sz = z_c / (1.f + __expf(-z_c));
      yvh[(size_t)rc * 512 + d] = __float2bfloat16((y + Dd * u_c) * sz);
      r += stepw;
    }
  } else {
    for (int i = 0; i < CLEN; i++) {
      const float* row = dbl + (size_t)r * 48 + 16;
      float dt_c = dtv, u_c = uv, z_c = zv;
      int rc = r;
      if (i < CLEN - 1) {
        dtv = __bfloat162float(dtbh[(size_t)(r + stepw) * 512 + d]);
        uv  = __bfloat162float(xch[(size_t)(r + stepw) * 512 + d]);
        zv  = __bfloat162float(xzh[(size_t)(r + stepw) * 1024 + 512 + d]);
      }
      float dtu = dt_c * u_c;
      float y = 0.f;
      #pragma unroll
      for (int n = 0; n < 16; n++) {
        float g = __expf(dt_c * a[n]);
        h[n] = fmaf(g, h[n], dtu * row[n]);
        y = fmaf(h[n], row[16 + n], y);
      }
      float sz = z_c / (1.f + __expf(-z_c));
      yvh[(size_t)rc * 512 + d] = __float2bfloat16((y + Dd * u_c) * sz);
      r += stepw;
    }
  }
}

extern "C" void kernel_launch(void* const* d_in, const int* in_sizes, int n_in,
                              void* d_out, int out_size, void* d_ws, size_t ws_size,
                              hipStream_t stream)
{
  const float* x = (const float*)d_in[0];
  const float* nw[2]     = {(const float*)d_in[1],  (const float*)d_in[11]};
  const float* inp[2]    = {(const float*)d_in[2],  (const float*)d_in[12]};
  const float* cw[2]     = {(const float*)d_in[3],  (const float*)d_in[13]};
  const float* cb[2]     = {(const float*)d_in[4],  (const float*)d_in[14]};
  const float* xp[2]     = {(const float*)d_in[5],  (const float*)d_in[15]};
  const float* dtw[2]    = {(const float*)d_in[6],  (const float*)d_in[16]};
  const float* dtbias[2] = {(const float*)d_in[7],  (const float*)d_in[17]};
  const float* alog[2]   = {(const float*)d_in[8],  (const float*)d_in[18]};
  const float* dvec[2]   = {(const float*)d_in[9],  (const float*)d_in[19]};
  const float* outp[2]   = {(const float*)d_in[10], (const float*)d_in[20]};

  float* ws = (float*)d_ws;
  size_t F = 0;
  __hip_bfloat16* xzh = (__hip_bfloat16*)(ws + F);      // bf16 2*8192*1024
  F += (size_t)2 * 8192 * 512;
  __hip_bfloat16* xch = (__hip_bfloat16*)(ws + F);      // bf16 2*8192*512
  F += (size_t)2 * 8192 * 256;
  float* dbl = ws + F;  F += (size_t)2 * 8192 * 48;
  __hip_bfloat16* dtbh = (__hip_bfloat16*)(ws + F);     // bf16 2*8192*512
  F += (size_t)2 * 8192 * 256;
  __hip_bfloat16* Ac = (__hip_bfloat16*)(ws + F);       // bf16 4*NCHUNK*8192
  F += (size_t)2 * NCHUNK * 8192;
  __hip_bfloat16* Bc = (__hip_bfloat16*)(ws + F);       // bf16 4*NCHUNK*8192
  F += (size_t)2 * NCHUNK * 8192;
  __hip_bfloat16* yvh = (__hip_bfloat16*)(ws + F);      // bf16 2*8192*512
  F += (size_t)2 * 8192 * 256;
  __hip_bfloat16* xnh = (__hip_bfloat16*)(ws + F);      // bf16 2*8192*256
  F += (size_t)2 * 8192 * 128;
  __hip_bfloat16* wb  = (__hip_bfloat16*)(ws + F);      // bf16 835584
  F += 835584 / 2;
  __hip_bfloat16* HinB = (__hip_bfloat16*)d_out;  // 8.39M bf16 = d_out exactly
  float* out = (float*)d_out;

  __hip_bfloat16* w_in[2]  = {wb,            wb + 262144};
  __hip_bfloat16* w_out[2] = {wb + 524288,   wb + 655360};
  __hip_bfloat16* w_xp[2]  = {wb + 786432,   wb + 811008};

  cast_weights<<<dim3(3264), 256, 0, stream>>>(
      inp[0], inp[1], outp[0], outp[1], xp[0], xp[1], wb);

  rmsnorm_kernel<<<dim3(8192), 256, 0, stream>>>(x, nw[0], nw[1], xnh);

  // in_proj: (8192x256)bf16 @ (1024x256)^T bf16 -> bf16 (8192x1024), both dirs
  gemm_mfma<<<dim3(64, 8, 2), 256, 0, stream>>>(
      xnh, (size_t)8192 * 256, 256,
      w_in[0], w_in[1], 256,
      xzh, (size_t)8192 * 1024, 1024,
      8192, 1024, 256, 0, nullptr, 0, 1);

  conv_silu_kernel<<<dim3(256, 2), 256, 0, stream>>>(
      xzh, cw[0], cb[0], cw[1], cb[1], xch);

  // x_proj: (8192x512)bf16 @ (48x512)^T bf16 -> f32 (8192x48), both dirs
  gemm_mfma<<<dim3(64, 1, 2), 256, 0, stream>>>(
      xch, (size_t)8192 * 512, 512,
      w_xp[0], w_xp[1], 512,
      dbl, (size_t)8192 * 48, 48,
      8192, 48, 512, 0, nullptr, 0, 0);

  // dt: (8192x16[lda48]) @ (512x16)^T f32 -> softplus(+bias) -> bf16, both dirs
  gemm_bt<<<dim3(128, 8, 2), 256, 0, stream>>>(
      dbl, (size_t)8192 * 48, 48,
      dtw[0], dtw[1], 16,
      dtbh, (size_t)8192 * 512, 512,
      8192, 512, 16, 1, dtbias[0], dtbias[1], 1);

  scan_part1<<<dim3(2, NCHUNK, 4), 256, 0, stream>>>(
      xch, dtbh, dbl, alog[0], alog[1], Ac, Bc);
  scan_mid<<<dim3(128), 256, 0, stream>>>(Ac, Bc, HinB);
  scan_part2<<<dim3(2, NCHUNK, 4), 256, 0, stream>>>(
      xzh, xch, dtbh, dbl, alog[0], alog[1], dvec[0], dvec[1], HinB, yvh);

  // out_proj: (8192x512)bf16 @ (256x512)^T bf16 + x -> out, both dirs
  gemm_mfma<<<dim3(64, 2, 2), 256, 0, stream>>>(
      yvh, (size_t)8192 * 512, 512,
      w_out[0], w_out[1], 512,
      out, (size_t)256, 512,
      8192, 256, 512, 2, x, 256, 0);
}